// Round 9
// baseline (220.420 us; speedup 1.0000x reference)
//
#include <hip/hip_runtime.h>
#include <math.h>

// Problem constants (fixed by reference)
#define B_ 2
#define S_ 2048
#define E_ 1024
#define H_ 16
#define D_ 64
#define M_ (B_ * S_)
// HEAD_DIM * -0.5 = -32 (faithful source bug) folded with 1/ln2 (exp2-domain
// softmax). Folded into Wk at convert time.
#define SC2 (-46.166241308446828f)

typedef unsigned short u16;
typedef _Float16 f16;
typedef __attribute__((ext_vector_type(8))) _Float16 f16x8;   // 4 VGPRs
typedef __attribute__((ext_vector_type(2))) __fp16 fp16x2_n;  // builtin ret type
typedef __attribute__((ext_vector_type(16))) float f32x16;    // 32x32 MFMA acc

static __device__ __forceinline__ f32x16 mfma_h(f16x8 a, f16x8 b, f32x16 c) {
    return __builtin_amdgcn_mfma_f32_32x32x16_f16(a, b, c, 0, 0, 0);
}
static __device__ __forceinline__ u16 f16bits(f16 h) {
    union { f16 h; u16 u; } c; c.h = h; return c.u;
}
static __device__ __forceinline__ unsigned pack2(u16 a, u16 b) {
    return (unsigned)a | ((unsigned)b << 16);
}
// One v_cvt_pkrtz_f16_f32: packs two floats to two fp16 (RTZ; P in [0,1]).
static __device__ __forceinline__ unsigned pkrtz(float a, float b) {
    fp16x2_n h = __builtin_amdgcn_cvt_pkrtz(a, b);
    unsigned u; __builtin_memcpy(&u, &h, 4); return u;
}
// v_permlane32_swap_b32: new a[32:63] = old b[0:31]; new b[0:31] = old a[32:63].
static __device__ __forceinline__ void pl32swap(unsigned &a, unsigned &b) {
    asm volatile("v_permlane32_swap_b32 %0, %1" : "+v"(a), "+v"(b));
}
#define ROWMAP(r, hh) (((r) & 3) + ((((r) >> 2)) << 3) + ((hh) << 2))

// ============================================================================
// One-shot fp32 -> fp16 hi (+ lo-residual where needed). SC2 folded into Wk.
// x, Wk, Wv: hi+lo. Wo: hi only (final GEMM is hi-only).
// ============================================================================
__global__ __launch_bounds__(256)
void convert_split(const float* __restrict__ x, const float* __restrict__ Wk,
                   const float* __restrict__ Wv, const float* __restrict__ Wo,
                   u16* __restrict__ Xh, u16* __restrict__ Xl,
                   u16* __restrict__ Wkh, u16* __restrict__ Wkl,
                   u16* __restrict__ Wvh, u16* __restrict__ Wvl,
                   u16* __restrict__ Woh)
{
    const int blk = blockIdx.x;
    const float* src; u16 *dh, *dl; int base; float sc = 1.0f; bool wantlo = true;
    if (blk < 4096)      { src = x;  dh = Xh;  dl = Xl;  base = blk; }
    else if (blk < 5120) { src = Wk; dh = Wkh; dl = Wkl; base = blk - 4096; sc = SC2; }
    else if (blk < 6144) { src = Wv; dh = Wvh; dl = Wvl; base = blk - 5120; }
    else                 { src = Wo; dh = Woh; dl = Woh; base = blk - 6144; wantlo = false; }
    const size_t off = ((size_t)base * 256 + threadIdx.x) * 4;
    const float4 v = *(const float4*)(src + off);
    const float f[4] = {v.x * sc, v.y * sc, v.z * sc, v.w * sc};
    u16 h4[4], l4[4];
#pragma unroll
    for (int i = 0; i < 4; ++i) {
        const f16 h = (f16)f[i];
        h4[i] = f16bits(h);
        l4[i] = f16bits((f16)(f[i] - (float)h));
    }
    *(uint2*)(dh + off) = make_uint2(pack2(h4[0], h4[1]), pack2(h4[2], h4[3]));
    if (wantlo)
        *(uint2*)(dl + off) = make_uint2(pack2(l4[0], l4[1]), pack2(l4[2], l4[3]));
}

// ============================================================================
// GEMM C = A @ W^T, 32x32x16 fp16 MFMA, hi/lo fp16 inputs.  (R7 state: both
// MODEs < 67us after round-halving; round-count model confirmed.)
// MODE 0: fused K+V projection, BK=64, 6 arrays = 99KB dynamic LDS, 16 rounds.
// MODE 1: O @ Wo^T, BK=128, 2 arrays = 66KB dynamic LDS, 8 rounds.
// 1024 thr / 16 waves, __launch_bounds__(1024,4). Wave layout: 4m x 2n
// quadrants of 32x64 x 2-way K-SPLIT (ws), fp32 merge via LDS. Register
// prefetch of tile k+1. Grid (8,32)=256 blocks.
// ============================================================================
#define CSB 1032            // (128+1)*8 u16 chunk stride (pad -> spread banks)

template<int MODE>
__global__ __launch_bounds__(1024, 4)
void gemm_f(const u16* __restrict__ Ah_, const u16* __restrict__ Al_,
            const u16* __restrict__ Bkh_, const u16* __restrict__ Bkl_,
            const u16* __restrict__ Bvh_, const u16* __restrict__ Bvl_,
            u16* __restrict__ Khg, u16* __restrict__ Klg,
            u16* __restrict__ Vhg, u16* __restrict__ Vtg,
            float* __restrict__ Cout)
{
    constexpr int BK   = (MODE == 0 ? 64 : 128);
    constexpr int NCH  = BK / 8;                // 8 or 16 chunks
    constexpr int NKK  = NCH / 4;               // 2 or 4 per wave-half
    constexpr int ARRX = NCH * CSB;             // 8256 or 16512 u16
    constexpr int NIT  = E_ / BK;               // 16 or 8
    extern __shared__ u16 stage[];              // 99KB / 66KB dynamic

    const int tid = threadIdx.x;
    const int w = tid >> 6, l31 = tid & 31, hh = (tid >> 5) & 1;
    const int wt = w & 7, ws = w >> 3;          // 4m x 2n quadrant / k-split half
    const int wm = (wt >> 1) << 5, wn = (wt & 1) << 6;
    const int m0 = blockIdx.y * 128, n0 = blockIdx.x * 128;
    const int ch8 = (ws << 1) + hh;             // wave-half's base k-subchunk

    // staging: rows 0..127 (tid>>3), chunks 0..7 (tid&7); MODE 1 also +8.
    const int sr = tid >> 3, sch = tid & 7;
    const size_t gA = (size_t)(m0 + sr) * E_ + (sch << 3);
    const size_t gB = (size_t)(n0 + sr) * E_ + (sch << 3);
    const int slo = sch * CSB + sr * 8;

    f32x16 acc1[2], acc2[2];
#pragma unroll
    for (int nt = 0; nt < 2; ++nt)
#pragma unroll
        for (int r = 0; r < 16; ++r) {
            acc1[nt][r] = 0.f;
            if constexpr (MODE == 0) acc2[nt][r] = 0.f;
        }

    constexpr int NPF = (MODE == 0 ? 6 : 4);
    f16x8 pf[NPF];
    auto load_tile = [&](int k0) {
        if constexpr (MODE == 0) {
            pf[0] = *(const f16x8*)(Ah_ + gA + k0);
            pf[1] = *(const f16x8*)(Al_ + gA + k0);
            pf[2] = *(const f16x8*)(Bkh_ + gB + k0);
            pf[3] = *(const f16x8*)(Bkl_ + gB + k0);
            pf[4] = *(const f16x8*)(Bvh_ + gB + k0);
            pf[5] = *(const f16x8*)(Bvl_ + gB + k0);
        } else {
            pf[0] = *(const f16x8*)(Ah_ + gA + k0);
            pf[1] = *(const f16x8*)(Ah_ + gA + k0 + 64);
            pf[2] = *(const f16x8*)(Bkh_ + gB + k0);
            pf[3] = *(const f16x8*)(Bkh_ + gB + k0 + 64);
        }
    };
    auto store_tile = [&]() {
        if constexpr (MODE == 0) {
#pragma unroll
            for (int a = 0; a < 6; ++a)
                *(f16x8*)&stage[a * ARRX + slo] = pf[a];
        } else {
            *(f16x8*)&stage[slo] = pf[0];
            *(f16x8*)&stage[(sch + 8) * CSB + sr * 8] = pf[1];
            *(f16x8*)&stage[ARRX + slo] = pf[2];
            *(f16x8*)&stage[ARRX + (sch + 8) * CSB + sr * 8] = pf[3];
        }
    };

    load_tile(0);
    for (int it = 0; it < NIT; ++it) {
        store_tile();
        __syncthreads();
        if (it + 1 < NIT) load_tile((it + 1) * BK);   // prefetch under compute

#pragma unroll
        for (int kk = 0; kk < NKK; ++kk) {
            const int co = (ch8 + (kk << 2)) * CSB;
            const int offx = co + (wm + l31) * 8;
            const f16x8 xh = *(const f16x8*)&stage[0 * ARRX + offx];
            f16x8 xl;
            if constexpr (MODE == 0) xl = *(const f16x8*)&stage[1 * ARRX + offx];
#pragma unroll
            for (int nt = 0; nt < 2; ++nt) {
                const int ro = co + (wn + (nt << 5) + l31) * 8;
                if constexpr (MODE == 0) {
                    const f16x8 bkh = *(const f16x8*)&stage[2 * ARRX + ro];
                    const f16x8 bkl = *(const f16x8*)&stage[3 * ARRX + ro];
                    const f16x8 bvh = *(const f16x8*)&stage[4 * ARRX + ro];
                    const f16x8 bvl = *(const f16x8*)&stage[5 * ARRX + ro];
                    acc1[nt] = mfma_h(xh, bkh, acc1[nt]);
                    acc1[nt] = mfma_h(xh, bkl, acc1[nt]);
                    acc1[nt] = mfma_h(xl, bkh, acc1[nt]);
                    acc2[nt] = mfma_h(xh, bvh, acc2[nt]);
                    acc2[nt] = mfma_h(xh, bvl, acc2[nt]);
                    acc2[nt] = mfma_h(xl, bvh, acc2[nt]);
                } else {
                    const f16x8 bh = *(const f16x8*)&stage[ARRX + ro];
                    acc1[nt] = mfma_h(xh, bh, acc1[nt]);
                }
            }
        }
        __syncthreads();   // reads done before next store_tile overwrites
    }

    // K-split merge via LDS (32KB rounds: one (array,nt) per round), ws1 -> ws0.
    float* red = (float*)stage;
    constexpr int NR = (MODE == 0 ? 4 : 2);
#pragma unroll
    for (int rd = 0; rd < NR; ++rd) {
        const int ntr = rd & 1;
        f32x16* A = (MODE == 0 && rd >= 2) ? &acc2[ntr] : &acc1[ntr];
        __syncthreads();
        if (ws == 1) {
#pragma unroll
            for (int r = 0; r < 16; ++r)
                red[(wt << 10) + (r << 6) + (hh << 5) + l31] = (*A)[r];
        }
        __syncthreads();
        if (ws == 0) {
#pragma unroll
            for (int r = 0; r < 16; ++r)
                (*A)[r] += red[(wt << 10) + (r << 6) + (hh << 5) + l31];
        }
    }
    if (ws != 0) return;

    // Epilogue (ws0, 8 waves cover 128x128). C/D map: col=lane&31, row=ROWMAP.
#pragma unroll
    for (int nt = 0; nt < 2; ++nt) {
        const int n = n0 + wn + (nt << 5) + l31;
        if constexpr (MODE == 1) {
#pragma unroll
            for (int r = 0; r < 16; ++r) {
                const int m = m0 + wm + ROWMAP(r, hh);
                Cout[(size_t)m * E_ + n] = acc1[nt][r];
            }
        } else {
            const int hd = n >> 6, d = n & 63;
            const int b = m0 >> 11;             // block never crosses batch
            u16 vb16[16];
#pragma unroll
            for (int r = 0; r < 16; ++r) {
                const int s = (m0 + wm + ROWMAP(r, hh)) & (S_ - 1);
                const size_t ib = (((size_t)(b * H_ + hd) << 11) + s) * D_ + d;
                const float kv = acc1[nt][r];   // SC2 already folded
                const f16 kh = (f16)kv;
                Khg[ib] = f16bits(kh);
                Klg[ib] = f16bits((f16)(kv - (float)kh));
                const f16 vh = (f16)acc2[nt][r];
                vb16[r] = f16bits(vh);
                Vhg[ib] = vb16[r];
            }
            const size_t vtb = ((size_t)(b * H_ + hd) * D_ + d) << 11;
#pragma unroll
            for (int g = 0; g < 4; ++g) {
                const int s0 = ((m0 + wm) & (S_ - 1)) + (g << 3) + (hh << 2);
                *(uint2*)&Vtg[vtb + s0] =
                    make_uint2(pack2(vb16[4 * g], vb16[4 * g + 1]),
                               pack2(vb16[4 * g + 2], vb16[4 * g + 3]));
            }
        }
    }
}

// ============================================================================
// Attention: logits2 = Ks@V^T, base-2 online softmax, O = P@V. All fp16.
// R8 lesson: fewer/bigger rounds is NEUTRAL for attn (dependent chain:
// ds_read -> St MFMA -> softmax VALU -> PV MFMA; serial is serial). The dead
// ~30% is LOCKSTEP: 1 block/CU means all waves hit the same barrier/phase.
//
// R9: 2 INDEPENDENT BLOCKS PER CU. 256 thr / 4 waves x 32 s-rows = 128
// s-rows/block; grid (16,32) = 512 blocks = 2 blocks/CU. Waves/CU unchanged
// (8 = 2/SIMD) but each SIMD hosts one wave from EACH block - no shared
// barrier -> block A's softmax/barrier gaps filled by block B's MFMA (m114).
// Memory: K rows disjoint across blocks (no dup); V per head re-staged by 16
// blocks (vs 8) but all-V = 16MB, L3-resident -> FETCH ~flat (vs R2's z-split
// which doubled the concurrent working set). LDS 33.3KB static dbuf x 2
// blocks = 66.6KB <= 160KB/CU. VGPR ~84 at 256-reg budget (launch_bounds
// (256,2); R6 lesson: 128-reg cap spills this body).
// Per-s-row op order identical to R3 -> bit-identical absmax.
//
// O^T orientation: PV computes D[m=d][n=s], A = Vt (staged), B = P^T built
// in-register via 16 cvt_pkrtz + 8 v_permlane32_swap_b32 (T12); no sP,
// per-lane alpha/linv. sV double-buffered, 1 barrier/iter. St 2-PASS dual
// accumulator chains (Vh*Ksh, Vh*Ksl); V-lo dropped. Ballot-skip dead tiles.
// ============================================================================
#define CSA 520             // (64+1)*8 u16
#define VA  (8 * CSA)       // one V array: 4160 u16

__global__ __launch_bounds__(256, 2)
void attn_mfma(const u16* __restrict__ Kh, const u16* __restrict__ Kl,
               const u16* __restrict__ Vh, const u16* __restrict__ Vt,
               u16* __restrict__ Obuf)
{
    __shared__ u16 sV[4 * VA];          // [buf][Vh | Vt], double-buffered

    const int tid = threadIdx.x;
    const int w = tid >> 6, l31 = tid & 31, hh = (tid >> 5) & 1;
    const int bh = blockIdx.y;
    const int sbase = blockIdx.x * 128 + (w << 5);
    const int sg = sbase + l31;

    // K fragments (SC2 pre-folded): B[n=s][k=d], hi/lo, loop-invariant
    f16x8 kfh[4], kfl[4];
    {
        const size_t kb = ((size_t)bh * S_ + sg) * D_;
#pragma unroll
        for (int ks = 0; ks < 4; ++ks) {
            const int db = (ks << 4) + (hh << 3);
            kfh[ks] = *(const f16x8*)(Kh + kb + db);
            kfl[ks] = *(const f16x8*)(Kl + kb + db);
        }
    }

    f32x16 oacc[2];                     // O^T: row d = ROWMAP+32nt, col s = l31
#pragma unroll
    for (int r = 0; r < 16; ++r) { oacc[0][r] = 0.f; oacc[1][r] = 0.f; }
    float m_i = -INFINITY, l_i = 0.f;

    // staging: 256 thr x 2 chunk-pairs cover 64 rows x 8 chunks per array
    const int rr = tid >> 2, cb = (tid & 3) << 1;  // row 0..63, chunks cb,cb+1
    const size_t gn = ((size_t)bh * S_ + rr) * D_ + (cb << 3);
    const size_t gt = ((size_t)bh * D_ + rr) * S_ + (cb << 3);
    const int slo = cb * CSA + rr * 8;

    f16x8 pv[4];
    auto load_tile = [&](int it2) {
        const size_t t0 = (size_t)it2 << 6;
        pv[0] = *(const f16x8*)(Vh + gn + t0 * D_);
        pv[1] = *(const f16x8*)(Vh + gn + t0 * D_ + 8);
        pv[2] = *(const f16x8*)(Vt + gt + t0);
        pv[3] = *(const f16x8*)(Vt + gt + t0 + 8);
    };
    auto store_tile = [&](int nb) {
        *(f16x8*)&sV[nb + slo] = pv[0];
        *(f16x8*)&sV[nb + slo + CSA] = pv[1];
        *(f16x8*)&sV[nb + VA + slo] = pv[2];
        *(f16x8*)&sV[nb + VA + slo + CSA] = pv[3];
    };

    load_tile(0);
    store_tile(0);
    __syncthreads();

    for (int it = 0; it < 32; ++it) {
        const int vb = (it & 1) * (2 * VA);
        const int nb = ((it + 1) & 1) * (2 * VA);
        if (it + 1 < 32) load_tile(it + 1);    // global->reg prefetch

        // St[t][s] = sum_d V[t][d]*Ks[s][d]  (2-pass, dual chains)
        f32x16 sta[2], stb[2];
#pragma unroll
        for (int r = 0; r < 16; ++r) {
            sta[0][r] = 0.f; sta[1][r] = 0.f;
            stb[0][r] = 0.f; stb[1][r] = 0.f;
        }
#pragma unroll
        for (int ks = 0; ks < 4; ++ks) {
            const int ch = (ks << 1) + hh;
#pragma unroll
            for (int mt = 0; mt < 2; ++mt) {
                const f16x8 av = *(const f16x8*)&sV[vb + ch * CSA + ((mt << 5) + l31) * 8];
                sta[mt] = mfma_h(av, kfh[ks], sta[mt]);
                stb[mt] = mfma_h(av, kfl[ks], stb[mt]);
            }
        }
#pragma unroll
        for (int mt = 0; mt < 2; ++mt)
#pragma unroll
            for (int r = 0; r < 16; ++r) sta[mt][r] += stb[mt][r];

        // Online softmax (base 2) over t for col s = l31
        float tmax = -INFINITY;
#pragma unroll
        for (int mt = 0; mt < 2; ++mt)
#pragma unroll
            for (int r = 0; r < 16; ++r) tmax = fmaxf(tmax, sta[mt][r]);
        tmax = fmaxf(tmax, __shfl_xor(tmax, 32));
        const float mnew = fmaxf(m_i, tmax);
        const float alpha = __builtin_amdgcn_exp2f(m_i - mnew);  // first tile: 0
        m_i = mnew;
        // cmask==0  =>  mnew==m_i for every lane  =>  alpha==1: skip all.
        const unsigned long long cmask = __ballot(tmax >= mnew - 30.f);

        if (cmask) {
            float rsum = 0.f;
#pragma unroll
            for (int mt = 0; mt < 2; ++mt)
#pragma unroll
                for (int r = 0; r < 16; ++r) {
                    const float p = __builtin_amdgcn_exp2f(sta[mt][r] - mnew);
                    sta[mt][r] = p;
                    rsum += p;
                }
            rsum += __shfl_xor(rsum, 32);
            l_i = l_i * alpha + rsum;

            // alpha rescale: per-lane (oacc col = s = l31)
#pragma unroll
            for (int r = 0; r < 16; ++r) { oacc[0][r] *= alpha; oacc[1][r] *= alpha; }

            // pack P to fp16: pa[mt][q] = (t0,t0+1), pb = (t0+2,t0+3),
            // t0 = 32mt+8q+4hh (own hh)
            unsigned pa[2][4], pb[2][4];
#pragma unroll
            for (int mt = 0; mt < 2; ++mt)
#pragma unroll
                for (int q = 0; q < 4; ++q) {
                    pa[mt][q] = pkrtz(sta[mt][4 * q + 0], sta[mt][4 * q + 1]);
                    pb[mt][q] = pkrtz(sta[mt][4 * q + 2], sta[mt][4 * q + 3]);
                }

            // PV: O^T[d][s] += Vt[d][t] * P^T[t][s], 4 chunks of K=16
#pragma unroll
            for (int ks = 0; ks < 4; ++ks) {
                const int mt = ks >> 1, kk = ks & 1;
                unsigned w0 = pa[mt][2 * kk], w2v = pa[mt][2 * kk + 1];
                pl32swap(w0, w2v);
                unsigned w1 = pb[mt][2 * kk], w3v = pb[mt][2 * kk + 1];
                pl32swap(w1, w3v);
                union { unsigned u[4]; f16x8 v; } bw;
                bw.u[0] = w0; bw.u[1] = w1; bw.u[2] = w2v; bw.u[3] = w3v;
                const int ch = (ks << 1) + hh;
#pragma unroll
                for (int nt = 0; nt < 2; ++nt) {
                    const f16x8 vtf = *(const f16x8*)&sV[vb + VA + ch * CSA + ((nt << 5) + l31) * 8];
                    oacc[nt] = mfma_h(vtf, bw.v, oacc[nt]);
                }
            }
        }

        if (it + 1 < 32) store_tile(nb);       // stage next tile into other buf
        __syncthreads();
    }

    // Epilogue: per-lane normalize (l_i is per-s = per-lane), store O fp16 [M,E]
    const float linv = (l_i > 0.f) ? (1.0f / l_i) : 0.f;
    const int b = bh >> 4;
    const int hd = bh & 15;
    u16* Or = Obuf + ((size_t)b * S_ + sg) * E_ + (hd << 6);
#pragma unroll
    for (int nt = 0; nt < 2; ++nt)
#pragma unroll
        for (int q = 0; q < 4; ++q) {
            const int d0 = (nt << 5) + (q << 3) + (hh << 2);
            u16 c[4];
#pragma unroll
            for (int j = 0; j < 4; ++j)
                c[j] = f16bits((f16)(oacc[nt][4 * q + j] * linv));
            *(uint2*)&Or[d0] = make_uint2(pack2(c[0], c[1]), pack2(c[2], c[3]));
        }
}

// ============================================================================
// Workspace (~58 MB):
//   0M Xh | 8M Xl (aliased by Obuf after gemm_kv) | 16M Wkh | 18M Wkl
//   20M Wvh | 22M Wvl | 24M Woh | 26M Kh | 34M Kl | 42M Vh | 50M Vt
// ============================================================================
extern "C" void kernel_launch(void* const* d_in, const int* in_sizes, int n_in,
                              void* d_out, int out_size, void* d_ws, size_t ws_size,
                              hipStream_t stream)
{
    (void)in_sizes; (void)n_in; (void)out_size; (void)ws_size;
    const float* x  = (const float*)d_in[0];
    // d_in[1] = Wq: computed-but-unused in reference; skipped.
    const float* Wk = (const float*)d_in[2];
    const float* Wv = (const float*)d_in[3];
    const float* Wo = (const float*)d_in[4];
    float* out = (float*)d_out;

    char* ws = (char*)d_ws;
    const size_t MB = 1u << 20;
    u16* Xh  = (u16*)(ws + 0 * MB);
    u16* Xl  = (u16*)(ws + 8 * MB);
    u16* Wkh = (u16*)(ws + 16 * MB);
    u16* Wkl = (u16*)(ws + 18 * MB);
    u16* Wvh = (u16*)(ws + 20 * MB);
    u16* Wvl = (u16*)(ws + 22 * MB);
    u16* Woh = (u16*)(ws + 24 * MB);
    u16* Kh  = (u16*)(ws + 26 * MB);
    u16* Kl  = (u16*)(ws + 34 * MB);
    u16* Vh  = (u16*)(ws + 42 * MB);
    u16* Vt  = (u16*)(ws + 50 * MB);
    u16* Obuf = Xl;        // x-lo dead after gemm_kv

    // Dynamic-LDS sizes (gemms only; attn is static 33.3KB).
    const int lds0 = 6 * (8 * CSB) * (int)sizeof(u16);    // 99072 B
    const int lds1 = 2 * (16 * CSB) * (int)sizeof(u16);   // 66048 B
    static bool attr_done = false;
    if (!attr_done) {
        hipFuncSetAttribute(reinterpret_cast<const void*>(&gemm_f<0>),
                            hipFuncAttributeMaxDynamicSharedMemorySize, lds0);
        hipFuncSetAttribute(reinterpret_cast<const void*>(&gemm_f<1>),
                            hipFuncAttributeMaxDynamicSharedMemorySize, lds1);
        attr_done = true;
    }

    convert_split<<<7168, 256, 0, stream>>>(x, Wk, Wv, Wo,
                                            Xh, Xl, Wkh, Wkl, Wvh, Wvl, Woh);
    gemm_f<0><<<dim3(E_ / 128, M_ / 128), 1024, lds0, stream>>>(
        Xh, Xl, Wkh, Wkl, Wvh, Wvl, Kh, Kl, Vh, Vt, nullptr);
    attn_mfma<<<dim3(S_ / 128, B_ * H_), 256, 0, stream>>>(Kh, Kl, Vh, Vt, Obuf);
    gemm_f<1><<<dim3(E_ / 128, M_ / 128), 1024, lds1, stream>>>(
        Obuf, Obuf, Woh, Woh, Woh, Woh,
        nullptr, nullptr, nullptr, nullptr, out);
}

// Round 10
// 216.817 us; speedup vs baseline: 1.0166x; 1.0166x over previous
//
#include <hip/hip_runtime.h>
#include <math.h>

// Problem constants (fixed by reference)
#define B_ 2
#define S_ 2048
#define E_ 1024
#define H_ 16
#define D_ 64
#define M_ (B_ * S_)
// HEAD_DIM * -0.5 = -32 (faithful source bug) folded with 1/ln2 (exp2-domain
// softmax). Folded into Wk at convert time.
#define SC2 (-46.166241308446828f)

typedef unsigned short u16;
typedef _Float16 f16;
typedef __attribute__((ext_vector_type(8))) _Float16 f16x8;   // 4 VGPRs
typedef __attribute__((ext_vector_type(2))) __fp16 fp16x2_n;  // builtin ret type
typedef __attribute__((ext_vector_type(16))) float f32x16;    // 32x32 MFMA acc

static __device__ __forceinline__ f32x16 mfma_h(f16x8 a, f16x8 b, f32x16 c) {
    return __builtin_amdgcn_mfma_f32_32x32x16_f16(a, b, c, 0, 0, 0);
}
static __device__ __forceinline__ u16 f16bits(f16 h) {
    union { f16 h; u16 u; } c; c.h = h; return c.u;
}
static __device__ __forceinline__ unsigned pack2(u16 a, u16 b) {
    return (unsigned)a | ((unsigned)b << 16);
}
// One v_cvt_pkrtz_f16_f32: packs two floats to two fp16 (RTZ; P in [0,1]).
static __device__ __forceinline__ unsigned pkrtz(float a, float b) {
    fp16x2_n h = __builtin_amdgcn_cvt_pkrtz(a, b);
    unsigned u; __builtin_memcpy(&u, &h, 4); return u;
}
// v_permlane32_swap_b32: new a[32:63] = old b[0:31]; new b[0:31] = old a[32:63].
static __device__ __forceinline__ void pl32swap(unsigned &a, unsigned &b) {
    asm volatile("v_permlane32_swap_b32 %0, %1" : "+v"(a), "+v"(b));
}
#define ROWMAP(r, hh) (((r) & 3) + ((((r) >> 2)) << 3) + ((hh) << 2))

// ============================================================================
// One-shot fp32 -> fp16 hi (+ lo-residual where needed). SC2 folded into Wk.
// x, Wk, Wv: hi+lo. Wo: hi only (final GEMM is hi-only).
// ============================================================================
__global__ __launch_bounds__(256)
void convert_split(const float* __restrict__ x, const float* __restrict__ Wk,
                   const float* __restrict__ Wv, const float* __restrict__ Wo,
                   u16* __restrict__ Xh, u16* __restrict__ Xl,
                   u16* __restrict__ Wkh, u16* __restrict__ Wkl,
                   u16* __restrict__ Wvh, u16* __restrict__ Wvl,
                   u16* __restrict__ Woh)
{
    const int blk = blockIdx.x;
    const float* src; u16 *dh, *dl; int base; float sc = 1.0f; bool wantlo = true;
    if (blk < 4096)      { src = x;  dh = Xh;  dl = Xl;  base = blk; }
    else if (blk < 5120) { src = Wk; dh = Wkh; dl = Wkl; base = blk - 4096; sc = SC2; }
    else if (blk < 6144) { src = Wv; dh = Wvh; dl = Wvl; base = blk - 5120; }
    else                 { src = Wo; dh = Woh; dl = Woh; base = blk - 6144; wantlo = false; }
    const size_t off = ((size_t)base * 256 + threadIdx.x) * 4;
    const float4 v = *(const float4*)(src + off);
    const float f[4] = {v.x * sc, v.y * sc, v.z * sc, v.w * sc};
    u16 h4[4], l4[4];
#pragma unroll
    for (int i = 0; i < 4; ++i) {
        const f16 h = (f16)f[i];
        h4[i] = f16bits(h);
        l4[i] = f16bits((f16)(f[i] - (float)h));
    }
    *(uint2*)(dh + off) = make_uint2(pack2(h4[0], h4[1]), pack2(h4[2], h4[3]));
    if (wantlo)
        *(uint2*)(dl + off) = make_uint2(pack2(l4[0], l4[1]), pack2(l4[2], l4[3]));
}

// ============================================================================
// GEMM C = A @ W^T, 32x32x16 fp16 MFMA, hi/lo fp16 inputs.
// R7 model (confirmed): time ~ (# of waitcnt-drain barrier rounds).
// MODE 0: fused K+V projection, BK=64, 6 arrays = 99KB dynamic LDS,
//         16 rounds x 2 barriers (can't dbuf: 2x99KB > 160KB).
// MODE 1: O @ Wo^T, BK=128, 2 arrays x 2 LDS BUFFERS = 132KB dynamic,
//         8 rounds x ONE barrier (R10): store targets the other buffer, so
//         reads(it) complete before barrier(it) and stores(it+1) land in the
//         buffer consumed at it+2 -> single barrier per round is sufficient.
//         Drains 16 -> 8.
// 1024 thr / 16 waves, __launch_bounds__(1024,4). Wave layout: 4m x 2n
// quadrants of 32x64 x 2-way K-SPLIT (ws), fp32 merge via LDS. Register
// prefetch of tile k+1. Grid (8,32)=256 blocks.
// ============================================================================
#define CSB 1032            // (128+1)*8 u16 chunk stride (pad -> spread banks)

template<int MODE>
__global__ __launch_bounds__(1024, 4)
void gemm_f(const u16* __restrict__ Ah_, const u16* __restrict__ Al_,
            const u16* __restrict__ Bkh_, const u16* __restrict__ Bkl_,
            const u16* __restrict__ Bvh_, const u16* __restrict__ Bvl_,
            u16* __restrict__ Khg, u16* __restrict__ Klg,
            u16* __restrict__ Vhg, u16* __restrict__ Vtg,
            float* __restrict__ Cout)
{
    constexpr int BK   = (MODE == 0 ? 64 : 128);
    constexpr int NCH  = BK / 8;                // 8 or 16 chunks
    constexpr int NKK  = NCH / 4;               // 2 or 4 per wave-half
    constexpr int ARRX = NCH * CSB;             // 8256 or 16512 u16
    constexpr int NIT  = E_ / BK;               // 16 or 8
    extern __shared__ u16 stage[];              // 99KB / 132KB dynamic

    const int tid = threadIdx.x;
    const int w = tid >> 6, l31 = tid & 31, hh = (tid >> 5) & 1;
    const int wt = w & 7, ws = w >> 3;          // 4m x 2n quadrant / k-split half
    const int wm = (wt >> 1) << 5, wn = (wt & 1) << 6;
    const int m0 = blockIdx.y * 128, n0 = blockIdx.x * 128;
    const int ch8 = (ws << 1) + hh;             // wave-half's base k-subchunk

    // staging: rows 0..127 (tid>>3), chunks 0..7 (tid&7); MODE 1 also +8.
    const int sr = tid >> 3, sch = tid & 7;
    const size_t gA = (size_t)(m0 + sr) * E_ + (sch << 3);
    const size_t gB = (size_t)(n0 + sr) * E_ + (sch << 3);
    const int slo = sch * CSB + sr * 8;

    f32x16 acc1[2], acc2[2];
#pragma unroll
    for (int nt = 0; nt < 2; ++nt)
#pragma unroll
        for (int r = 0; r < 16; ++r) {
            acc1[nt][r] = 0.f;
            if constexpr (MODE == 0) acc2[nt][r] = 0.f;
        }

    constexpr int NPF = (MODE == 0 ? 6 : 4);
    f16x8 pf[NPF];
    auto load_tile = [&](int k0) {
        if constexpr (MODE == 0) {
            pf[0] = *(const f16x8*)(Ah_ + gA + k0);
            pf[1] = *(const f16x8*)(Al_ + gA + k0);
            pf[2] = *(const f16x8*)(Bkh_ + gB + k0);
            pf[3] = *(const f16x8*)(Bkl_ + gB + k0);
            pf[4] = *(const f16x8*)(Bvh_ + gB + k0);
            pf[5] = *(const f16x8*)(Bvl_ + gB + k0);
        } else {
            pf[0] = *(const f16x8*)(Ah_ + gA + k0);
            pf[1] = *(const f16x8*)(Ah_ + gA + k0 + 64);
            pf[2] = *(const f16x8*)(Bkh_ + gB + k0);
            pf[3] = *(const f16x8*)(Bkh_ + gB + k0 + 64);
        }
    };
    auto store_tile = [&](int bb) {             // bb = buffer base (u16 elems)
        if constexpr (MODE == 0) {
#pragma unroll
            for (int a = 0; a < 6; ++a)
                *(f16x8*)&stage[bb + a * ARRX + slo] = pf[a];
        } else {
            *(f16x8*)&stage[bb + slo] = pf[0];
            *(f16x8*)&stage[bb + (sch + 8) * CSB + sr * 8] = pf[1];
            *(f16x8*)&stage[bb + ARRX + slo] = pf[2];
            *(f16x8*)&stage[bb + ARRX + (sch + 8) * CSB + sr * 8] = pf[3];
        }
    };
    auto compute = [&](int bb) {
#pragma unroll
        for (int kk = 0; kk < NKK; ++kk) {
            const int co = bb + (ch8 + (kk << 2)) * CSB;
            const int offx = co + (wm + l31) * 8;
            const f16x8 xh = *(const f16x8*)&stage[0 * ARRX + offx];
            f16x8 xl;
            if constexpr (MODE == 0) xl = *(const f16x8*)&stage[1 * ARRX + offx];
#pragma unroll
            for (int nt = 0; nt < 2; ++nt) {
                const int ro = co + (wn + (nt << 5) + l31) * 8;
                if constexpr (MODE == 0) {
                    const f16x8 bkh = *(const f16x8*)&stage[2 * ARRX + ro];
                    const f16x8 bkl = *(const f16x8*)&stage[3 * ARRX + ro];
                    const f16x8 bvh = *(const f16x8*)&stage[4 * ARRX + ro];
                    const f16x8 bvl = *(const f16x8*)&stage[5 * ARRX + ro];
                    acc1[nt] = mfma_h(xh, bkh, acc1[nt]);
                    acc1[nt] = mfma_h(xh, bkl, acc1[nt]);
                    acc1[nt] = mfma_h(xl, bkh, acc1[nt]);
                    acc2[nt] = mfma_h(xh, bvh, acc2[nt]);
                    acc2[nt] = mfma_h(xh, bvl, acc2[nt]);
                    acc2[nt] = mfma_h(xl, bvh, acc2[nt]);
                } else {
                    const f16x8 bh = *(const f16x8*)&stage[ARRX + ro];
                    acc1[nt] = mfma_h(xh, bh, acc1[nt]);
                }
            }
        }
    };

    if constexpr (MODE == 0) {
        // Single-buffered, 2 barriers/round (LDS-capped).
        load_tile(0);
        for (int it = 0; it < NIT; ++it) {
            store_tile(0);
            __syncthreads();
            if (it + 1 < NIT) load_tile((it + 1) * BK);   // prefetch
            compute(0);
            __syncthreads();
        }
    } else {
        // Double-buffered, ONE barrier/round (drains 16 -> 8).
        load_tile(0);
        store_tile(0);
        __syncthreads();
        for (int it = 0; it < NIT; ++it) {
            const int cb = (it & 1) * (2 * ARRX);
            const int nb = ((it + 1) & 1) * (2 * ARRX);
            if (it + 1 < NIT) load_tile((it + 1) * BK);   // global->reg
            compute(cb);
            if (it + 1 < NIT) store_tile(nb);             // other buffer
            __syncthreads();
        }
    }

    // K-split merge via LDS (32KB rounds: one (array,nt) per round), ws1 -> ws0.
    float* red = (float*)stage;
    constexpr int NR = (MODE == 0 ? 4 : 2);
#pragma unroll
    for (int rd = 0; rd < NR; ++rd) {
        const int ntr = rd & 1;
        f32x16* A = (MODE == 0 && rd >= 2) ? &acc2[ntr] : &acc1[ntr];
        __syncthreads();
        if (ws == 1) {
#pragma unroll
            for (int r = 0; r < 16; ++r)
                red[(wt << 10) + (r << 6) + (hh << 5) + l31] = (*A)[r];
        }
        __syncthreads();
        if (ws == 0) {
#pragma unroll
            for (int r = 0; r < 16; ++r)
                (*A)[r] += red[(wt << 10) + (r << 6) + (hh << 5) + l31];
        }
    }
    if (ws != 0) return;

    // Epilogue (ws0, 8 waves cover 128x128). C/D map: col=lane&31, row=ROWMAP.
#pragma unroll
    for (int nt = 0; nt < 2; ++nt) {
        const int n = n0 + wn + (nt << 5) + l31;
        if constexpr (MODE == 1) {
#pragma unroll
            for (int r = 0; r < 16; ++r) {
                const int m = m0 + wm + ROWMAP(r, hh);
                Cout[(size_t)m * E_ + n] = acc1[nt][r];
            }
        } else {
            const int hd = n >> 6, d = n & 63;
            const int b = m0 >> 11;             // block never crosses batch
            u16 vb16[16];
#pragma unroll
            for (int r = 0; r < 16; ++r) {
                const int s = (m0 + wm + ROWMAP(r, hh)) & (S_ - 1);
                const size_t ib = (((size_t)(b * H_ + hd) << 11) + s) * D_ + d;
                const float kv = acc1[nt][r];   // SC2 already folded
                const f16 kh = (f16)kv;
                Khg[ib] = f16bits(kh);
                Klg[ib] = f16bits((f16)(kv - (float)kh));
                const f16 vh = (f16)acc2[nt][r];
                vb16[r] = f16bits(vh);
                Vhg[ib] = vb16[r];
            }
            const size_t vtb = ((size_t)(b * H_ + hd) * D_ + d) << 11;
#pragma unroll
            for (int g = 0; g < 4; ++g) {
                const int s0 = ((m0 + wm) & (S_ - 1)) + (g << 3) + (hh << 2);
                *(uint2*)&Vtg[vtb + s0] =
                    make_uint2(pack2(vb16[4 * g], vb16[4 * g + 1]),
                               pack2(vb16[4 * g + 2], vb16[4 * g + 3]));
            }
        }
    }
}

// ============================================================================
// Attention (R3-exact, best measured 64.9us). R4/R8/R9 lessons: pairing,
// bigger rounds, and independent co-resident blocks are ALL neutral/negative
// -> this dependent-chain structure at 2 waves/SIMD is at its scheduling
// floor; structure frozen this session.
// logits2 = Ks@V^T, base-2 online softmax, O = P@V. All fp16.
// 512 thr / 8 waves; 256 s-rows/block; wave w owns s in [32w,32w+32).
// Grid (8,32)=256 blocks. O^T orientation: PV computes D[m=d][n=s], A = Vt
// (staged), B = P^T built in-register via 16 cvt_pkrtz + 8
// v_permlane32_swap_b32 (T12); no sP, per-lane alpha/linv. sV double-
// buffered, 1 barrier/iter. St 2-PASS dual accumulator chains (Vh*Ksh,
// Vh*Ksl); V-lo dropped. Ballot-skip dead tiles. LDS 33.3KB static.
// ============================================================================
#define CSA 520             // (64+1)*8 u16
#define VA  (8 * CSA)       // one V array: 4160 u16

__global__ __launch_bounds__(512, 2)
void attn_mfma(const u16* __restrict__ Kh, const u16* __restrict__ Kl,
               const u16* __restrict__ Vh, const u16* __restrict__ Vt,
               u16* __restrict__ Obuf)
{
    __shared__ u16 sV[4 * VA];          // [buf][Vh | Vt], double-buffered

    const int tid = threadIdx.x;
    const int w = tid >> 6, l31 = tid & 31, hh = (tid >> 5) & 1;
    const int bh = blockIdx.y;
    const int sbase = blockIdx.x * 256 + (w << 5);
    const int sg = sbase + l31;

    // K fragments (SC2 pre-folded): B[n=s][k=d], hi/lo, loop-invariant
    f16x8 kfh[4], kfl[4];
    {
        const size_t kb = ((size_t)bh * S_ + sg) * D_;
#pragma unroll
        for (int ks = 0; ks < 4; ++ks) {
            const int db = (ks << 4) + (hh << 3);
            kfh[ks] = *(const f16x8*)(Kh + kb + db);
            kfl[ks] = *(const f16x8*)(Kl + kb + db);
        }
    }

    f32x16 oacc[2];                     // O^T: row d = ROWMAP+32nt, col s = l31
#pragma unroll
    for (int r = 0; r < 16; ++r) { oacc[0][r] = 0.f; oacc[1][r] = 0.f; }
    float m_i = -INFINITY, l_i = 0.f;

    const int rr = tid >> 3, cc = tid & 7;     // staging: row 0..63, chunk 0..7
    const size_t gn = ((size_t)bh * S_ + rr) * D_ + (cc << 3);
    const size_t gt = ((size_t)bh * D_ + rr) * S_ + (cc << 3);
    const int slo = cc * CSA + rr * 8;

    f16x8 pv[2];
    auto load_tile = [&](int it2) {
        const size_t t0 = (size_t)it2 << 6;
        pv[0] = *(const f16x8*)(Vh + gn + t0 * D_);
        pv[1] = *(const f16x8*)(Vt + gt + t0);
    };

    load_tile(0);
    *(f16x8*)&sV[slo] = pv[0];
    *(f16x8*)&sV[VA + slo] = pv[1];
    __syncthreads();

    for (int it = 0; it < 32; ++it) {
        const int vb = (it & 1) * (2 * VA);
        const int nb = ((it + 1) & 1) * (2 * VA);
        if (it + 1 < 32) load_tile(it + 1);    // global->reg prefetch

        // St[t][s] = sum_d V[t][d]*Ks[s][d]  (2-pass, dual chains)
        f32x16 sta[2], stb[2];
#pragma unroll
        for (int r = 0; r < 16; ++r) {
            sta[0][r] = 0.f; sta[1][r] = 0.f;
            stb[0][r] = 0.f; stb[1][r] = 0.f;
        }
#pragma unroll
        for (int ks = 0; ks < 4; ++ks) {
            const int ch = (ks << 1) + hh;
#pragma unroll
            for (int mt = 0; mt < 2; ++mt) {
                const f16x8 av = *(const f16x8*)&sV[vb + ch * CSA + ((mt << 5) + l31) * 8];
                sta[mt] = mfma_h(av, kfh[ks], sta[mt]);
                stb[mt] = mfma_h(av, kfl[ks], stb[mt]);
            }
        }
#pragma unroll
        for (int mt = 0; mt < 2; ++mt)
#pragma unroll
            for (int r = 0; r < 16; ++r) sta[mt][r] += stb[mt][r];

        // Online softmax (base 2) over t for col s = l31
        float tmax = -INFINITY;
#pragma unroll
        for (int mt = 0; mt < 2; ++mt)
#pragma unroll
            for (int r = 0; r < 16; ++r) tmax = fmaxf(tmax, sta[mt][r]);
        tmax = fmaxf(tmax, __shfl_xor(tmax, 32));
        const float mnew = fmaxf(m_i, tmax);
        const float alpha = __builtin_amdgcn_exp2f(m_i - mnew);  // first tile: 0
        m_i = mnew;
        // cmask==0  =>  mnew==m_i for every lane  =>  alpha==1: skip all.
        const unsigned long long cmask = __ballot(tmax >= mnew - 30.f);

        if (cmask) {
            float rsum = 0.f;
#pragma unroll
            for (int mt = 0; mt < 2; ++mt)
#pragma unroll
                for (int r = 0; r < 16; ++r) {
                    const float p = __builtin_amdgcn_exp2f(sta[mt][r] - mnew);
                    sta[mt][r] = p;
                    rsum += p;
                }
            rsum += __shfl_xor(rsum, 32);
            l_i = l_i * alpha + rsum;

            // alpha rescale: per-lane (oacc col = s = l31)
#pragma unroll
            for (int r = 0; r < 16; ++r) { oacc[0][r] *= alpha; oacc[1][r] *= alpha; }

            // pack P to fp16: pa[mt][q] = (t0,t0+1), pb = (t0+2,t0+3),
            // t0 = 32mt+8q+4hh (own hh)
            unsigned pa[2][4], pb[2][4];
#pragma unroll
            for (int mt = 0; mt < 2; ++mt)
#pragma unroll
                for (int q = 0; q < 4; ++q) {
                    pa[mt][q] = pkrtz(sta[mt][4 * q + 0], sta[mt][4 * q + 1]);
                    pb[mt][q] = pkrtz(sta[mt][4 * q + 2], sta[mt][4 * q + 3]);
                }

            // PV: O^T[d][s] += Vt[d][t] * P^T[t][s], 4 chunks of K=16
#pragma unroll
            for (int ks = 0; ks < 4; ++ks) {
                const int mt = ks >> 1, kk = ks & 1;
                unsigned w0 = pa[mt][2 * kk], w2v = pa[mt][2 * kk + 1];
                pl32swap(w0, w2v);
                unsigned w1 = pb[mt][2 * kk], w3v = pb[mt][2 * kk + 1];
                pl32swap(w1, w3v);
                union { unsigned u[4]; f16x8 v; } bw;
                bw.u[0] = w0; bw.u[1] = w1; bw.u[2] = w2v; bw.u[3] = w3v;
                const int ch = (ks << 1) + hh;
#pragma unroll
                for (int nt = 0; nt < 2; ++nt) {
                    const f16x8 vtf = *(const f16x8*)&sV[vb + VA + ch * CSA + ((nt << 5) + l31) * 8];
                    oacc[nt] = mfma_h(vtf, bw.v, oacc[nt]);
                }
            }
        }

        if (it + 1 < 32) {                     // stage next tile into other buf
            *(f16x8*)&sV[nb + slo] = pv[0];
            *(f16x8*)&sV[nb + VA + slo] = pv[1];
        }
        __syncthreads();
    }

    // Epilogue: per-lane normalize (l_i is per-s = per-lane), store O fp16 [M,E]
    const float linv = (l_i > 0.f) ? (1.0f / l_i) : 0.f;
    const int b = bh >> 4;
    const int hd = bh & 15;
    u16* Or = Obuf + ((size_t)b * S_ + sg) * E_ + (hd << 6);
#pragma unroll
    for (int nt = 0; nt < 2; ++nt)
#pragma unroll
        for (int q = 0; q < 4; ++q) {
            const int d0 = (nt << 5) + (q << 3) + (hh << 2);
            u16 c[4];
#pragma unroll
            for (int j = 0; j < 4; ++j)
                c[j] = f16bits((f16)(oacc[nt][4 * q + j] * linv));
            *(uint2*)&Or[d0] = make_uint2(pack2(c[0], c[1]), pack2(c[2], c[3]));
        }
}

// ============================================================================
// Workspace (~58 MB):
//   0M Xh | 8M Xl (aliased by Obuf after gemm_kv) | 16M Wkh | 18M Wkl
//   20M Wvh | 22M Wvl | 24M Woh | 26M Kh | 34M Kl | 42M Vh | 50M Vt
// ============================================================================
extern "C" void kernel_launch(void* const* d_in, const int* in_sizes, int n_in,
                              void* d_out, int out_size, void* d_ws, size_t ws_size,
                              hipStream_t stream)
{
    (void)in_sizes; (void)n_in; (void)out_size; (void)ws_size;
    const float* x  = (const float*)d_in[0];
    // d_in[1] = Wq: computed-but-unused in reference; skipped.
    const float* Wk = (const float*)d_in[2];
    const float* Wv = (const float*)d_in[3];
    const float* Wo = (const float*)d_in[4];
    float* out = (float*)d_out;

    char* ws = (char*)d_ws;
    const size_t MB = 1u << 20;
    u16* Xh  = (u16*)(ws + 0 * MB);
    u16* Xl  = (u16*)(ws + 8 * MB);
    u16* Wkh = (u16*)(ws + 16 * MB);
    u16* Wkl = (u16*)(ws + 18 * MB);
    u16* Wvh = (u16*)(ws + 20 * MB);
    u16* Wvl = (u16*)(ws + 22 * MB);
    u16* Woh = (u16*)(ws + 24 * MB);
    u16* Kh  = (u16*)(ws + 26 * MB);
    u16* Kl  = (u16*)(ws + 34 * MB);
    u16* Vh  = (u16*)(ws + 42 * MB);
    u16* Vt  = (u16*)(ws + 50 * MB);
    u16* Obuf = Xl;        // x-lo dead after gemm_kv

    // Dynamic-LDS sizes (gemms only; attn is static 33.3KB).
    const int lds0 = 6 * (8 * CSB) * (int)sizeof(u16);        // 99072 B
    const int lds1 = 2 * 2 * (16 * CSB) * (int)sizeof(u16);   // 132096 B (dbuf)
    static bool attr_done = false;
    if (!attr_done) {
        hipFuncSetAttribute(reinterpret_cast<const void*>(&gemm_f<0>),
                            hipFuncAttributeMaxDynamicSharedMemorySize, lds0);
        hipFuncSetAttribute(reinterpret_cast<const void*>(&gemm_f<1>),
                            hipFuncAttributeMaxDynamicSharedMemorySize, lds1);
        attr_done = true;
    }

    convert_split<<<7168, 256, 0, stream>>>(x, Wk, Wv, Wo,
                                            Xh, Xl, Wkh, Wkl, Wvh, Wvl, Woh);
    gemm_f<0><<<dim3(E_ / 128, M_ / 128), 1024, lds0, stream>>>(
        Xh, Xl, Wkh, Wkl, Wvh, Wvl, Kh, Kl, Vh, Vt, nullptr);
    attn_mfma<<<dim3(S_ / 256, B_ * H_), 512, 0, stream>>>(Kh, Kl, Vh, Vt, Obuf);
    gemm_f<1><<<dim3(E_ / 128, M_ / 128), 1024, lds1, stream>>>(
        Obuf, Obuf, Woh, Woh, Woh, Woh,
        nullptr, nullptr, nullptr, nullptr, out);
}

// Round 12
// 209.407 us; speedup vs baseline: 1.0526x; 1.0354x over previous
//
#include <hip/hip_runtime.h>
#include <math.h>

// Problem constants (fixed by reference)
#define B_ 2
#define S_ 2048
#define E_ 1024
#define H_ 16
#define D_ 64
#define M_ (B_ * S_)
// HEAD_DIM * -0.5 = -32 (faithful source bug) folded with 1/ln2 (exp2-domain
// softmax). Folded into Wk at convert time.
#define SC2 (-46.166241308446828f)

typedef unsigned short u16;
typedef _Float16 f16;
typedef __attribute__((ext_vector_type(8))) _Float16 f16x8;   // 4 VGPRs
typedef __attribute__((ext_vector_type(2))) __fp16 fp16x2_n;  // builtin ret type
typedef __attribute__((ext_vector_type(16))) float f32x16;    // 32x32 MFMA acc

static __device__ __forceinline__ f32x16 mfma_h(f16x8 a, f16x8 b, f32x16 c) {
    return __builtin_amdgcn_mfma_f32_32x32x16_f16(a, b, c, 0, 0, 0);
}
static __device__ __forceinline__ u16 f16bits(f16 h) {
    union { f16 h; u16 u; } c; c.h = h; return c.u;
}
static __device__ __forceinline__ unsigned pack2(u16 a, u16 b) {
    return (unsigned)a | ((unsigned)b << 16);
}
// One v_cvt_pkrtz_f16_f32: packs two floats to two fp16 (RTZ; P in [0,1]).
static __device__ __forceinline__ unsigned pkrtz(float a, float b) {
    fp16x2_n h = __builtin_amdgcn_cvt_pkrtz(a, b);
    unsigned u; __builtin_memcpy(&u, &h, 4); return u;
}
// v_permlane32_swap_b32: new a[32:63] = old b[0:31]; new b[0:31] = old a[32:63].
static __device__ __forceinline__ void pl32swap(unsigned &a, unsigned &b) {
    asm volatile("v_permlane32_swap_b32 %0, %1" : "+v"(a), "+v"(b));
}
// T4 counted-vmcnt barrier (R12: hardened — compiler-understood builtin
// barrier, guide-verified 8-phase pattern). LDS visibility (lgkmcnt 0) +
// rendezvous WITHOUT draining vmcnt: register-destined global loads stay in
// flight across the barrier. __syncthreads() would emit s_waitcnt vmcnt(0)
// and re-expose the full loaded-HBM latency every tile.
static __device__ __forceinline__ void lgkm_bar() {
    asm volatile("s_waitcnt lgkmcnt(0)" ::: "memory");
    __builtin_amdgcn_s_barrier();
}
#define ROWMAP(r, hh) (((r) & 3) + ((((r) >> 2)) << 3) + ((hh) << 2))

// ============================================================================
// One-shot fp32 -> fp16 hi (+ lo-residual where needed). SC2 folded into Wk.
// x, Wk, Wv: hi+lo. Wo: hi only (final GEMM is hi-only).
// ============================================================================
__global__ __launch_bounds__(256)
void convert_split(const float* __restrict__ x, const float* __restrict__ Wk,
                   const float* __restrict__ Wv, const float* __restrict__ Wo,
                   u16* __restrict__ Xh, u16* __restrict__ Xl,
                   u16* __restrict__ Wkh, u16* __restrict__ Wkl,
                   u16* __restrict__ Wvh, u16* __restrict__ Wvl,
                   u16* __restrict__ Woh)
{
    const int blk = blockIdx.x;
    const float* src; u16 *dh, *dl; int base; float sc = 1.0f; bool wantlo = true;
    if (blk < 4096)      { src = x;  dh = Xh;  dl = Xl;  base = blk; }
    else if (blk < 5120) { src = Wk; dh = Wkh; dl = Wkl; base = blk - 4096; sc = SC2; }
    else if (blk < 6144) { src = Wv; dh = Wvh; dl = Wvl; base = blk - 5120; }
    else                 { src = Wo; dh = Woh; dl = Woh; base = blk - 6144; wantlo = false; }
    const size_t off = ((size_t)base * 256 + threadIdx.x) * 4;
    const float4 v = *(const float4*)(src + off);
    const float f[4] = {v.x * sc, v.y * sc, v.z * sc, v.w * sc};
    u16 h4[4], l4[4];
#pragma unroll
    for (int i = 0; i < 4; ++i) {
        const f16 h = (f16)f[i];
        h4[i] = f16bits(h);
        l4[i] = f16bits((f16)(f[i] - (float)h));
    }
    *(uint2*)(dh + off) = make_uint2(pack2(h4[0], h4[1]), pack2(h4[2], h4[3]));
    if (wantlo)
        *(uint2*)(dl + off) = make_uint2(pack2(l4[0], l4[1]), pack2(l4[2], l4[3]));
}

// ============================================================================
// GEMM C = A @ W^T, 32x32x16 fp16 MFMA, hi/lo fp16 inputs.
// R7 model (confirmed): time ~ (# of waitcnt-drain barrier rounds).
// R12: all K-loop barriers are lgkm-only (loads stay in flight across them).
// MODE 0: fused K+V projection, BK=64, 6 arrays = 99KB dynamic LDS,
//         single-buffered (2x99KB > 160KB), depth-1 reg prefetch.
// MODE 1: O @ Wo^T, BK=128, 2 arrays x 2 LDS buffers = 132KB dynamic,
//         depth-2 parity reg prefetch (pf0/pf1, static indexing) -> each
//         round's ds_write waits a COUNTED vmcnt with ~2-round window.
// 1024 thr / 16 waves, __launch_bounds__(1024,4). Wave layout: 4m x 2n
// quadrants of 32x64 x 2-way K-SPLIT (ws), fp32 merge via LDS. Grid 256 blk.
// ============================================================================
#define CSB 1032            // (128+1)*8 u16 chunk stride (pad -> spread banks)

template<int MODE>
__global__ __launch_bounds__(1024, 4)
void gemm_f(const u16* __restrict__ Ah_, const u16* __restrict__ Al_,
            const u16* __restrict__ Bkh_, const u16* __restrict__ Bkl_,
            const u16* __restrict__ Bvh_, const u16* __restrict__ Bvl_,
            u16* __restrict__ Khg, u16* __restrict__ Klg,
            u16* __restrict__ Vhg, u16* __restrict__ Vtg,
            float* __restrict__ Cout)
{
    constexpr int BK   = (MODE == 0 ? 64 : 128);
    constexpr int NCH  = BK / 8;                // 8 or 16 chunks
    constexpr int NKK  = NCH / 4;               // 2 or 4 per wave-half
    constexpr int ARRX = NCH * CSB;             // 8256 or 16512 u16
    constexpr int NIT  = E_ / BK;               // 16 or 8
    extern __shared__ u16 stage[];              // 99KB / 132KB dynamic

    const int tid = threadIdx.x;
    const int w = tid >> 6, l31 = tid & 31, hh = (tid >> 5) & 1;
    const int wt = w & 7, ws = w >> 3;          // 4m x 2n quadrant / k-split half
    const int wm = (wt >> 1) << 5, wn = (wt & 1) << 6;
    const int m0 = blockIdx.y * 128, n0 = blockIdx.x * 128;
    const int ch8 = (ws << 1) + hh;             // wave-half's base k-subchunk

    // staging: rows 0..127 (tid>>3), chunks 0..7 (tid&7); MODE 1 also +8.
    const int sr = tid >> 3, sch = tid & 7;
    const size_t gA = (size_t)(m0 + sr) * E_ + (sch << 3);
    const size_t gB = (size_t)(n0 + sr) * E_ + (sch << 3);
    const int slo = sch * CSB + sr * 8;

    f32x16 acc1[2], acc2[2];
#pragma unroll
    for (int nt = 0; nt < 2; ++nt)
#pragma unroll
        for (int r = 0; r < 16; ++r) {
            acc1[nt][r] = 0.f;
            if constexpr (MODE == 0) acc2[nt][r] = 0.f;
        }

    constexpr int NPF = (MODE == 0 ? 6 : 4);
    f16x8 pf0[NPF], pf1[NPF];
    auto load_tile = [&](int k0, f16x8* pf) {
        if constexpr (MODE == 0) {
            pf[0] = *(const f16x8*)(Ah_ + gA + k0);
            pf[1] = *(const f16x8*)(Al_ + gA + k0);
            pf[2] = *(const f16x8*)(Bkh_ + gB + k0);
            pf[3] = *(const f16x8*)(Bkl_ + gB + k0);
            pf[4] = *(const f16x8*)(Bvh_ + gB + k0);
            pf[5] = *(const f16x8*)(Bvl_ + gB + k0);
        } else {
            pf[0] = *(const f16x8*)(Ah_ + gA + k0);
            pf[1] = *(const f16x8*)(Ah_ + gA + k0 + 64);
            pf[2] = *(const f16x8*)(Bkh_ + gB + k0);
            pf[3] = *(const f16x8*)(Bkh_ + gB + k0 + 64);
        }
    };
    auto store_tile = [&](int bb, f16x8* pf) {  // bb = buffer base (u16 elems)
        if constexpr (MODE == 0) {
#pragma unroll
            for (int a = 0; a < 6; ++a)
                *(f16x8*)&stage[bb + a * ARRX + slo] = pf[a];
        } else {
            *(f16x8*)&stage[bb + slo] = pf[0];
            *(f16x8*)&stage[bb + (sch + 8) * CSB + sr * 8] = pf[1];
            *(f16x8*)&stage[bb + ARRX + slo] = pf[2];
            *(f16x8*)&stage[bb + ARRX + (sch + 8) * CSB + sr * 8] = pf[3];
        }
    };
    auto compute = [&](int bb) {
#pragma unroll
        for (int kk = 0; kk < NKK; ++kk) {
            const int co = bb + (ch8 + (kk << 2)) * CSB;
            const int offx = co + (wm + l31) * 8;
            const f16x8 xh = *(const f16x8*)&stage[0 * ARRX + offx];
            f16x8 xl;
            if constexpr (MODE == 0) xl = *(const f16x8*)&stage[1 * ARRX + offx];
#pragma unroll
            for (int nt = 0; nt < 2; ++nt) {
                const int ro = co + (wn + (nt << 5) + l31) * 8;
                if constexpr (MODE == 0) {
                    const f16x8 bkh = *(const f16x8*)&stage[2 * ARRX + ro];
                    const f16x8 bkl = *(const f16x8*)&stage[3 * ARRX + ro];
                    const f16x8 bvh = *(const f16x8*)&stage[4 * ARRX + ro];
                    const f16x8 bvl = *(const f16x8*)&stage[5 * ARRX + ro];
                    acc1[nt] = mfma_h(xh, bkh, acc1[nt]);
                    acc1[nt] = mfma_h(xh, bkl, acc1[nt]);
                    acc1[nt] = mfma_h(xl, bkh, acc1[nt]);
                    acc2[nt] = mfma_h(xh, bvh, acc2[nt]);
                    acc2[nt] = mfma_h(xh, bvl, acc2[nt]);
                    acc2[nt] = mfma_h(xl, bvh, acc2[nt]);
                } else {
                    const f16x8 bh = *(const f16x8*)&stage[ARRX + ro];
                    acc1[nt] = mfma_h(xh, bh, acc1[nt]);
                }
            }
        }
    };

    if constexpr (MODE == 0) {
        // Single-buffered; lgkm-only barriers keep load(it+1) in flight
        // across the post-compute barrier (its wait lands at next store).
        load_tile(0, pf0);
        for (int it = 0; it < NIT; ++it) {
            store_tile(0, pf0);
            lgkm_bar();
            if (it + 1 < NIT) load_tile((it + 1) * BK, pf0);
            compute(0);
            lgkm_bar();
        }
    } else {
        // Double-buffered, depth-2 parity prefetch, one lgkm barrier/round.
        load_tile(0, pf0);
        store_tile(0, pf0);            // prologue vmcnt wait (once)
        load_tile(BK, pf1);
        lgkm_bar();
        for (int p = 0; p < NIT / 2; ++p) {
            const int e = 2 * p;
            if (e + 2 < NIT) load_tile((e + 2) * BK, pf0);
            compute(0);
            store_tile(2 * ARRX, pf1);             // tile e+1 -> buf1
            lgkm_bar();
            if (e + 3 < NIT) load_tile((e + 3) * BK, pf1);
            compute(2 * ARRX);
            if (e + 2 < NIT) store_tile(0, pf0);   // tile e+2 -> buf0
            lgkm_bar();
        }
    }

    // K-split merge via LDS (32KB rounds: one (array,nt) per round), ws1 -> ws0.
    // __syncthreads (full drain) here: cold path, safety first.
    float* red = (float*)stage;
    constexpr int NR = (MODE == 0 ? 4 : 2);
#pragma unroll
    for (int rd = 0; rd < NR; ++rd) {
        const int ntr = rd & 1;
        f32x16* A = (MODE == 0 && rd >= 2) ? &acc2[ntr] : &acc1[ntr];
        __syncthreads();
        if (ws == 1) {
#pragma unroll
            for (int r = 0; r < 16; ++r)
                red[(wt << 10) + (r << 6) + (hh << 5) + l31] = (*A)[r];
        }
        __syncthreads();
        if (ws == 0) {
#pragma unroll
            for (int r = 0; r < 16; ++r)
                (*A)[r] += red[(wt << 10) + (r << 6) + (hh << 5) + l31];
        }
    }
    if (ws != 0) return;

    // Epilogue (ws0, 8 waves cover 128x128). C/D map: col=lane&31, row=ROWMAP.
#pragma unroll
    for (int nt = 0; nt < 2; ++nt) {
        const int n = n0 + wn + (nt << 5) + l31;
        if constexpr (MODE == 1) {
#pragma unroll
            for (int r = 0; r < 16; ++r) {
                const int m = m0 + wm + ROWMAP(r, hh);
                Cout[(size_t)m * E_ + n] = acc1[nt][r];
            }
        } else {
            const int hd = n >> 6, d = n & 63;
            const int b = m0 >> 11;             // block never crosses batch
            u16 vb16[16];
#pragma unroll
            for (int r = 0; r < 16; ++r) {
                const int s = (m0 + wm + ROWMAP(r, hh)) & (S_ - 1);
                const size_t ib = (((size_t)(b * H_ + hd) << 11) + s) * D_ + d;
                const float kv = acc1[nt][r];   // SC2 already folded
                const f16 kh = (f16)kv;
                Khg[ib] = f16bits(kh);
                Klg[ib] = f16bits((f16)(kv - (float)kh));
                const f16 vh = (f16)acc2[nt][r];
                vb16[r] = f16bits(vh);
                Vhg[ib] = vb16[r];
            }
            const size_t vtb = ((size_t)(b * H_ + hd) * D_ + d) << 11;
#pragma unroll
            for (int g = 0; g < 4; ++g) {
                const int s0 = ((m0 + wm) & (S_ - 1)) + (g << 3) + (hh << 2);
                *(uint2*)&Vtg[vtb + s0] =
                    make_uint2(pack2(vb16[4 * g], vb16[4 * g + 1]),
                               pack2(vb16[4 * g + 2], vb16[4 * g + 3]));
            }
        }
    }
}

// ============================================================================
// Attention (R3 compute body, frozen; R4/R8/R9: all work-rearrangements
// neutral). R12 = R11 hardened: T4 counted-vmcnt pipeline -- per-tile cost
// ~4900 cyc vs ~1000 cyc of work; the gap is loaded-HBM latency re-exposed
// by the vmcnt(0) drain inside __syncthreads every tile. Fix: lgkm-only
// barriers (builtin s_barrier; loads stay in flight) + depth-2 parity reg
// prefetch (pv0/pv1, static indexing) -> ds_write waits a COUNTED vmcnt
// with a ~2-tile window. Identical per-tile op order -> bit-identical
// numerics (absmax 0.0859375).
// 512 thr / 8 waves; 256 s-rows/block; grid (8,32)=256 blocks.
// O^T orientation: PV computes D[m=d][n=s], A = Vt (staged), B = P^T built
// in-register via 16 cvt_pkrtz + 8 v_permlane32_swap_b32 (T12); per-lane
// alpha/linv. sV double-buffered (2 x [Vh|Vt] = 33.3KB static).
// ============================================================================
#define CSA 520             // (64+1)*8 u16
#define VA  (8 * CSA)       // one V array: 4160 u16

__global__ __launch_bounds__(512, 2)
void attn_mfma(const u16* __restrict__ Kh, const u16* __restrict__ Kl,
               const u16* __restrict__ Vh, const u16* __restrict__ Vt,
               u16* __restrict__ Obuf)
{
    __shared__ u16 sV[4 * VA];          // [buf][Vh | Vt], double-buffered

    const int tid = threadIdx.x;
    const int w = tid >> 6, l31 = tid & 31, hh = (tid >> 5) & 1;
    const int bh = blockIdx.y;
    const int sbase = blockIdx.x * 256 + (w << 5);
    const int sg = sbase + l31;

    // K fragments (SC2 pre-folded): B[n=s][k=d], hi/lo, loop-invariant
    f16x8 kfh[4], kfl[4];
    {
        const size_t kb = ((size_t)bh * S_ + sg) * D_;
#pragma unroll
        for (int ks = 0; ks < 4; ++ks) {
            const int db = (ks << 4) + (hh << 3);
            kfh[ks] = *(const f16x8*)(Kh + kb + db);
            kfl[ks] = *(const f16x8*)(Kl + kb + db);
        }
    }

    f32x16 oacc[2];                     // O^T: row d = ROWMAP+32nt, col s = l31
#pragma unroll
    for (int r = 0; r < 16; ++r) { oacc[0][r] = 0.f; oacc[1][r] = 0.f; }
    float m_i = -INFINITY, l_i = 0.f;

    const int rr = tid >> 3, cc = tid & 7;     // staging: row 0..63, chunk 0..7
    const size_t gn = ((size_t)bh * S_ + rr) * D_ + (cc << 3);
    const size_t gt = ((size_t)bh * D_ + rr) * S_ + (cc << 3);
    const int slo = cc * CSA + rr * 8;

    f16x8 pv0[2], pv1[2];
    auto load_t = [&](int it2, f16x8* pv) {
        const size_t t0 = (size_t)it2 << 6;
        pv[0] = *(const f16x8*)(Vh + gn + t0 * D_);
        pv[1] = *(const f16x8*)(Vt + gt + t0);
    };
    auto store_t = [&](int nb, f16x8* pv) {
        *(f16x8*)&sV[nb + slo] = pv[0];
        *(f16x8*)&sV[nb + VA + slo] = pv[1];
    };

    // One full tile: St (2-pass dual chains) -> online softmax -> P^T -> PV.
    auto PROC = [&](int base) {
        f32x16 sta[2], stb[2];
#pragma unroll
        for (int r = 0; r < 16; ++r) {
            sta[0][r] = 0.f; sta[1][r] = 0.f;
            stb[0][r] = 0.f; stb[1][r] = 0.f;
        }
#pragma unroll
        for (int ks = 0; ks < 4; ++ks) {
            const int ch = (ks << 1) + hh;
#pragma unroll
            for (int mt = 0; mt < 2; ++mt) {
                const f16x8 av = *(const f16x8*)&sV[base + ch * CSA + ((mt << 5) + l31) * 8];
                sta[mt] = mfma_h(av, kfh[ks], sta[mt]);
                stb[mt] = mfma_h(av, kfl[ks], stb[mt]);
            }
        }
#pragma unroll
        for (int mt = 0; mt < 2; ++mt)
#pragma unroll
            for (int r = 0; r < 16; ++r) sta[mt][r] += stb[mt][r];

        float tmax = -INFINITY;
#pragma unroll
        for (int mt = 0; mt < 2; ++mt)
#pragma unroll
            for (int r = 0; r < 16; ++r) tmax = fmaxf(tmax, sta[mt][r]);
        tmax = fmaxf(tmax, __shfl_xor(tmax, 32));
        const float mnew = fmaxf(m_i, tmax);
        const float alpha = __builtin_amdgcn_exp2f(m_i - mnew);  // first tile: 0
        m_i = mnew;
        // cmask==0  =>  mnew==m_i for every lane  =>  alpha==1: skip all.
        const unsigned long long cmask = __ballot(tmax >= mnew - 30.f);

        if (cmask) {
            float rsum = 0.f;
#pragma unroll
            for (int mt = 0; mt < 2; ++mt)
#pragma unroll
                for (int r = 0; r < 16; ++r) {
                    const float p = __builtin_amdgcn_exp2f(sta[mt][r] - mnew);
                    sta[mt][r] = p;
                    rsum += p;
                }
            rsum += __shfl_xor(rsum, 32);
            l_i = l_i * alpha + rsum;

            // alpha rescale: per-lane (oacc col = s = l31)
#pragma unroll
            for (int r = 0; r < 16; ++r) { oacc[0][r] *= alpha; oacc[1][r] *= alpha; }

            // pack P to fp16: pa[mt][q] = (t0,t0+1), pb = (t0+2,t0+3),
            // t0 = 32mt+8q+4hh (own hh)
            unsigned pa[2][4], pb[2][4];
#pragma unroll
            for (int mt = 0; mt < 2; ++mt)
#pragma unroll
                for (int q = 0; q < 4; ++q) {
                    pa[mt][q] = pkrtz(sta[mt][4 * q + 0], sta[mt][4 * q + 1]);
                    pb[mt][q] = pkrtz(sta[mt][4 * q + 2], sta[mt][4 * q + 3]);
                }

            // PV: O^T[d][s] += Vt[d][t] * P^T[t][s], 4 chunks of K=16
#pragma unroll
            for (int ks = 0; ks < 4; ++ks) {
                const int mt = ks >> 1, kk = ks & 1;
                unsigned w0 = pa[mt][2 * kk], w2v = pa[mt][2 * kk + 1];
                pl32swap(w0, w2v);
                unsigned w1 = pb[mt][2 * kk], w3v = pb[mt][2 * kk + 1];
                pl32swap(w1, w3v);
                union { unsigned u[4]; f16x8 v; } bw;
                bw.u[0] = w0; bw.u[1] = w1; bw.u[2] = w2v; bw.u[3] = w3v;
                const int ch = (ks << 1) + hh;
#pragma unroll
                for (int nt = 0; nt < 2; ++nt) {
                    const f16x8 vtf = *(const f16x8*)&sV[base + VA + ch * CSA + ((nt << 5) + l31) * 8];
                    oacc[nt] = mfma_h(vtf, bw.v, oacc[nt]);
                }
            }
        }
    };

    // Pipeline invariant at tile it: buf[it&1] holds tile it (in LDS);
    // pv[(it+1)&1] holds tile it+1 (loaded, possibly in flight).
    load_t(0, pv0);
    store_t(0, pv0);               // prologue vmcnt wait (once)
    load_t(1, pv1);
    lgkm_bar();

    for (int p = 0; p < 16; ++p) {
        const int e = 2 * p;
        // even tile e (buf0)
        if (e + 2 < 32) load_t(e + 2, pv0);
        PROC(0);
        store_t(2 * VA, pv1);                  // tile e+1 -> buf1 (counted vmcnt)
        lgkm_bar();
        // odd tile e+1 (buf1)
        if (e + 3 < 32) load_t(e + 3, pv1);
        PROC(2 * VA);
        if (e + 2 < 32) store_t(0, pv0);       // tile e+2 -> buf0
        lgkm_bar();
    }

    // Epilogue: per-lane normalize (l_i is per-s = per-lane), store O fp16 [M,E]
    const float linv = (l_i > 0.f) ? (1.0f / l_i) : 0.f;
    const int b = bh >> 4;
    const int hd = bh & 15;
    u16* Or = Obuf + ((size_t)b * S_ + sg) * E_ + (hd << 6);
#pragma unroll
    for (int nt = 0; nt < 2; ++nt)
#pragma unroll
        for (int q = 0; q < 4; ++q) {
            const int d0 = (nt << 5) + (q << 3) + (hh << 2);
            u16 c[4];
#pragma unroll
            for (int j = 0; j < 4; ++j)
                c[j] = f16bits((f16)(oacc[nt][4 * q + j] * linv));
            *(uint2*)&Or[d0] = make_uint2(pack2(c[0], c[1]), pack2(c[2], c[3]));
        }
}

// ============================================================================
// Workspace (~58 MB):
//   0M Xh | 8M Xl (aliased by Obuf after gemm_kv) | 16M Wkh | 18M Wkl
//   20M Wvh | 22M Wvl | 24M Woh | 26M Kh | 34M Kl | 42M Vh | 50M Vt
// ============================================================================
extern "C" void kernel_launch(void* const* d_in, const int* in_sizes, int n_in,
                              void* d_out, int out_size, void* d_ws, size_t ws_size,
                              hipStream_t stream)
{
    (void)in_sizes; (void)n_in; (void)out_size; (void)ws_size;
    const float* x  = (const float*)d_in[0];
    // d_in[1] = Wq: computed-but-unused in reference; skipped.
    const float* Wk = (const float*)d_in[2];
    const float* Wv = (const float*)d_in[3];
    const float* Wo = (const float*)d_in[4];
    float* out = (float*)d_out;

    char* ws = (char*)d_ws;
    const size_t MB = 1u << 20;
    u16* Xh  = (u16*)(ws + 0 * MB);
    u16* Xl  = (u16*)(ws + 8 * MB);
    u16* Wkh = (u16*)(ws + 16 * MB);
    u16* Wkl = (u16*)(ws + 18 * MB);
    u16* Wvh = (u16*)(ws + 20 * MB);
    u16* Wvl = (u16*)(ws + 22 * MB);
    u16* Woh = (u16*)(ws + 24 * MB);
    u16* Kh  = (u16*)(ws + 26 * MB);
    u16* Kl  = (u16*)(ws + 34 * MB);
    u16* Vh  = (u16*)(ws + 42 * MB);
    u16* Vt  = (u16*)(ws + 50 * MB);
    u16* Obuf = Xl;        // x-lo dead after gemm_kv

    // Dynamic-LDS sizes (gemms only; attn is static 33.3KB).
    const int lds0 = 6 * (8 * CSB) * (int)sizeof(u16);        // 99072 B
    const int lds1 = 2 * 2 * (16 * CSB) * (int)sizeof(u16);   // 132096 B (dbuf)
    static bool attr_done = false;
    if (!attr_done) {
        hipFuncSetAttribute(reinterpret_cast<const void*>(&gemm_f<0>),
                            hipFuncAttributeMaxDynamicSharedMemorySize, lds0);
        hipFuncSetAttribute(reinterpret_cast<const void*>(&gemm_f<1>),
                            hipFuncAttributeMaxDynamicSharedMemorySize, lds1);
        attr_done = true;
    }

    convert_split<<<7168, 256, 0, stream>>>(x, Wk, Wv, Wo,
                                            Xh, Xl, Wkh, Wkl, Wvh, Wvl, Woh);
    gemm_f<0><<<dim3(E_ / 128, M_ / 128), 1024, lds0, stream>>>(
        Xh, Xl, Wkh, Wkl, Wvh, Wvl, Kh, Kl, Vh, Vt, nullptr);
    attn_mfma<<<dim3(S_ / 256, B_ * H_), 512, 0, stream>>>(Kh, Kl, Vh, Vt, Obuf);
    gemm_f<1><<<dim3(E_ / 128, M_ / 128), 1024, lds1, stream>>>(
        Obuf, Obuf, Woh, Woh, Woh, Woh,
        nullptr, nullptr, nullptr, nullptr, out);
}